// Round 1
// baseline (320.609 us; speedup 1.0000x reference)
//
#include <hip/hip_runtime.h>

#define BN_EPS 1e-3f

// ---------------------------------------------------------------------------
// Submanifold 3x3x3 sparse conv (gather -> dense 27x16x16 matmul), voxel per
// thread, W broadcast from LDS in [k][o][c] layout. Optionally applies
// BN+ReLU (from a previous conv's stats) to the gathered input on the fly.
// Also accumulates per-channel sum / sumsq of the OUTPUT (pre-BN) for BN.
// ---------------------------------------------------------------------------
template<bool APPLY_BN>
__global__ __launch_bounds__(256)
void subm_conv_kernel(const float* __restrict__ x,    // [N,16] input features (raw y_prev if APPLY_BN)
                      const float* __restrict__ W,    // [27,16,16] (k,c,o)
                      const int*   __restrict__ nbr,  // [N,27], -1 = missing
                      const float* __restrict__ ss,   // [32]: scale[16], shift[16] (if APPLY_BN)
                      float* __restrict__ y,          // [N,16] output (pre-BN)
                      float* __restrict__ stats,      // [32]: sum[16], sumsq[16]
                      int N)
{
    __shared__ float wT[27 * 16 * 16];  // [k][o][c]
    __shared__ float sred[128];         // [sum|sq][4 waves][16 ch]

    // Load W transposed: wT[(k*16+o)*16 + c] = W[(k*16+c)*16 + o]
    for (int e = threadIdx.x; e < 27 * 256; e += 256) {
        int k = e >> 8, c = (e >> 4) & 15, o = e & 15;
        wT[(k * 16 + o) * 16 + c] = W[e];
    }
    __syncthreads();

    int n = blockIdx.x * 256 + threadIdx.x;
    float acc[16];
#pragma unroll
    for (int o = 0; o < 16; ++o) acc[o] = 0.f;

    if (n < N) {
        const int* nr = nbr + n * 27;
        for (int k = 0; k < 27; ++k) {
            int idx = nr[k];
            if (idx < 0) continue;
            const float4* xr = (const float4*)(x + (size_t)idx * 16);
            float xv[16];
            *(float4*)(xv + 0)  = xr[0];
            *(float4*)(xv + 4)  = xr[1];
            *(float4*)(xv + 8)  = xr[2];
            *(float4*)(xv + 12) = xr[3];
            if (APPLY_BN) {
#pragma unroll
                for (int c = 0; c < 16; ++c)
                    xv[c] = fmaxf(fmaf(xv[c], ss[c], ss[16 + c]), 0.f);
            }
            const float4* wk = (const float4*)(wT + k * 256);
#pragma unroll
            for (int o = 0; o < 16; ++o) {
                float4 w0 = wk[o * 4 + 0];
                float4 w1 = wk[o * 4 + 1];
                float4 w2 = wk[o * 4 + 2];
                float4 w3 = wk[o * 4 + 3];
                float s = acc[o];
                s = fmaf(xv[0],  w0.x, s);
                s = fmaf(xv[1],  w0.y, s);
                s = fmaf(xv[2],  w0.z, s);
                s = fmaf(xv[3],  w0.w, s);
                s = fmaf(xv[4],  w1.x, s);
                s = fmaf(xv[5],  w1.y, s);
                s = fmaf(xv[6],  w1.z, s);
                s = fmaf(xv[7],  w1.w, s);
                s = fmaf(xv[8],  w2.x, s);
                s = fmaf(xv[9],  w2.y, s);
                s = fmaf(xv[10], w2.z, s);
                s = fmaf(xv[11], w2.w, s);
                s = fmaf(xv[12], w3.x, s);
                s = fmaf(xv[13], w3.y, s);
                s = fmaf(xv[14], w3.z, s);
                s = fmaf(xv[15], w3.w, s);
                acc[o] = s;
            }
        }
        float4* yo = (float4*)(y + (size_t)n * 16);
        yo[0] = make_float4(acc[0],  acc[1],  acc[2],  acc[3]);
        yo[1] = make_float4(acc[4],  acc[5],  acc[6],  acc[7]);
        yo[2] = make_float4(acc[8],  acc[9],  acc[10], acc[11]);
        yo[3] = make_float4(acc[12], acc[13], acc[14], acc[15]);
    }

    // BN stats: wave shuffle reduce -> LDS -> per-block atomics.
    // Inactive (tail) lanes contribute 0.
    int lane = threadIdx.x & 63;
    int wv   = threadIdx.x >> 6;
#pragma unroll
    for (int o = 0; o < 16; ++o) {
        float s = acc[o];
        float q = acc[o] * acc[o];
        for (int off = 32; off; off >>= 1) {
            s += __shfl_down(s, off);
            q += __shfl_down(q, off);
        }
        if (lane == 0) {
            sred[wv * 16 + o]      = s;
            sred[64 + wv * 16 + o] = q;
        }
    }
    __syncthreads();
    if (threadIdx.x < 16) {
        int o = threadIdx.x;
        float s = sred[o] + sred[16 + o] + sred[32 + o] + sred[48 + o];
        float q = sred[64 + o] + sred[80 + o] + sred[96 + o] + sred[112 + o];
        atomicAdd(&stats[o], s);
        atomicAdd(&stats[16 + o], q);
    }
}

// mean/var -> scale/shift (fold g,b):  sc = g*rsqrt(var+eps), sh = b - mu*sc
__global__ void finalize_stats_kernel(const float* __restrict__ stats,
                                      const float* __restrict__ g,
                                      const float* __restrict__ b,
                                      float* __restrict__ ss, float invN)
{
    int o = threadIdx.x;
    if (o < 16) {
        float mu  = stats[o] * invN;
        float var = stats[16 + o] * invN - mu * mu;
        float sc  = g[o] * rsqrtf(var + BN_EPS);
        ss[o]      = sc;
        ss[16 + o] = b[o] - mu * sc;
    }
}

// Rows 0..N-1: relu(bn(y1)); rows N..2N-1: feat2 @ Wobo + bobo.
// atomicAdd into zero-initialized merged[U,16].
__global__ __launch_bounds__(256)
void scatter_kernel(const float* __restrict__ y1, const float* __restrict__ ss1,
                    const float* __restrict__ feat2, const float* __restrict__ Wobo,
                    const float* __restrict__ bobo, const int* __restrict__ seg,
                    float* __restrict__ merged, int N)
{
    int t = blockIdx.x * 256 + threadIdx.x;
    int r = t >> 4, o = t & 15;
    if (r >= 2 * N) return;
    float v;
    if (r < N) {
        v = fmaxf(fmaf(y1[(size_t)r * 16 + o], ss1[o], ss1[16 + o]), 0.f);
    } else {
        int m = r - N;
        v = bobo[o];
#pragma unroll
        for (int c = 0; c < 16; ++c)
            v = fmaf(feat2[(size_t)m * 16 + c], Wobo[c * 16 + o], v);
    }
    atomicAdd(&merged[(size_t)seg[r] * 16 + o], v);
}

// out[u,j] = merged[u,:16] @ Wf[:,j] + bf[j]
__global__ __launch_bounds__(256)
void final_gemm_kernel(const float* __restrict__ merged, const float* __restrict__ Wf,
                       const float* __restrict__ bf, float* __restrict__ out, int U)
{
    __shared__ float wf_s[16 * 128];
    for (int e = threadIdx.x; e < 2048; e += 256) wf_s[e] = Wf[e];
    __syncthreads();

    int t = blockIdx.x * 256 + threadIdx.x;
    int u = t >> 7, j = t & 127;
    if (u >= U) return;

    const float4* mr = (const float4*)(merged + (size_t)u * 16);
    float4 m0 = mr[0], m1 = mr[1], m2 = mr[2], m3 = mr[3];
    float s = bf[j];
    s = fmaf(m0.x, wf_s[0  * 128 + j], s);
    s = fmaf(m0.y, wf_s[1  * 128 + j], s);
    s = fmaf(m0.z, wf_s[2  * 128 + j], s);
    s = fmaf(m0.w, wf_s[3  * 128 + j], s);
    s = fmaf(m1.x, wf_s[4  * 128 + j], s);
    s = fmaf(m1.y, wf_s[5  * 128 + j], s);
    s = fmaf(m1.z, wf_s[6  * 128 + j], s);
    s = fmaf(m1.w, wf_s[7  * 128 + j], s);
    s = fmaf(m2.x, wf_s[8  * 128 + j], s);
    s = fmaf(m2.y, wf_s[9  * 128 + j], s);
    s = fmaf(m2.z, wf_s[10 * 128 + j], s);
    s = fmaf(m2.w, wf_s[11 * 128 + j], s);
    s = fmaf(m3.x, wf_s[12 * 128 + j], s);
    s = fmaf(m3.y, wf_s[13 * 128 + j], s);
    s = fmaf(m3.z, wf_s[14 * 128 + j], s);
    s = fmaf(m3.w, wf_s[15 * 128 + j], s);
    out[(size_t)u * 128 + j] = s;
}

extern "C" void kernel_launch(void* const* d_in, const int* in_sizes, int n_in,
                              void* d_out, int out_size, void* d_ws, size_t ws_size,
                              hipStream_t stream)
{
    const float* vf    = (const float*)d_in[0];
    const float* feat2 = (const float*)d_in[1];
    const float* W0    = (const float*)d_in[2];
    const float* g0    = (const float*)d_in[3];
    const float* b0    = (const float*)d_in[4];
    const float* W1    = (const float*)d_in[5];
    const float* g1    = (const float*)d_in[6];
    const float* b1    = (const float*)d_in[7];
    const float* Wobo  = (const float*)d_in[8];
    const float* bobo  = (const float*)d_in[9];
    const float* Wf    = (const float*)d_in[10];
    const float* bf    = (const float*)d_in[11];
    const int*   nbr   = (const int*)d_in[12];
    const int*   seg   = (const int*)d_in[13];

    int N = in_sizes[0] / 16;     // 100000
    int U = out_size / 128;       // num_segments

    float* out = (float*)d_out;
    float* ws  = (float*)d_ws;

    // Workspace layout (floats):
    float* y0     = ws;                          // N*16
    float* y1     = ws + (size_t)N * 16;         // N*16
    float* stats  = ws + (size_t)2 * N * 16;     // 64 (stats0 | stats1)
    float* ssb    = stats + 64;                  // 64 (ss0 | ss1)
    float* merged = ssb + 64;                    // U*16

    hipMemsetAsync(stats, 0, 64 * sizeof(float), stream);
    hipMemsetAsync(merged, 0, (size_t)U * 16 * sizeof(float), stream);

    int gb = (N + 255) / 256;
    subm_conv_kernel<false><<<gb, 256, 0, stream>>>(vf, W0, nbr, nullptr, y0, stats, N);
    finalize_stats_kernel<<<1, 64, 0, stream>>>(stats, g0, b0, ssb, 1.f / N);
    subm_conv_kernel<true><<<gb, 256, 0, stream>>>(y0, W1, nbr, ssb, y1, stats + 32, N);
    finalize_stats_kernel<<<1, 64, 0, stream>>>(stats + 32, g1, b1, ssb + 32, 1.f / N);
    scatter_kernel<<<(2 * N * 16 + 255) / 256, 256, 0, stream>>>(y1, ssb + 32, feat2, Wobo,
                                                                 bobo, seg, merged, N);
    final_gemm_kernel<<<((size_t)U * 128 + 255) / 256, 256, 0, stream>>>(merged, Wf, bf, out, U);
}